// Round 1
// baseline (5001.930 us; speedup 1.0000x reference)
//
#include <hip/hip_runtime.h>
#include <cstdint>
#include <cstddef>

// ---------------------------------------------------------------------------
// Vehicle detection pipeline (RPN conv -> heads -> topk -> NMS -> ROI -> FC)
// All fp32. B=2, C=960, H=20, W=40, A=12, PRE=1000, POST=500, POOL=7.
// ---------------------------------------------------------------------------

// ---------------- pad input for 3x3 SAME conv: (2,960,22,42) ----------------
__global__ __launch_bounds__(256) void pad_kernel(const float* __restrict__ f,
                                                  float* __restrict__ xp)
{
  int idx = blockIdx.x * 256 + threadIdx.x;
  const int total = 2 * 960 * 22 * 42;
  if (idx >= total) return;
  int xx = idx % 42;
  int r  = idx / 42;
  int yy = r % 22;
  int bc = r / 22;
  float v = 0.f;
  if (yy >= 1 && yy <= 20 && xx >= 1 && xx <= 40)
    v = f[bc * 800 + (yy - 1) * 40 + (xx - 1)];
  xp[idx] = v;
}

// ---------------- conv 3x3 as implicit GEMM: M=960(o), N=800(p), K=8640 -----
__global__ __launch_bounds__(256) void conv_kernel(const float* __restrict__ Wc,
                                                   const float* __restrict__ Xpad,
                                                   const float* __restrict__ bias,
                                                   float* __restrict__ T)
{
  __shared__ float As[16][64];
  __shared__ float Bs[16][64];
  int tid = threadIdx.x;
  int b  = blockIdx.z;
  int p0 = blockIdx.x * 64;   // pixel tile (13 tiles, last partial)
  int m0 = blockIdx.y * 64;   // out-channel tile (15 exact)
  int ty = tid >> 4, tx = tid & 15;
  int a_m = tid >> 2, a_k4 = (tid & 3) << 2;
  int b_k = tid >> 4, b_p4 = (tid & 15) << 2;
  const float* xb = Xpad + (size_t)b * 960 * 22 * 42;
  float acc[4][4] = {};
  for (int k0 = 0; k0 < 8640; k0 += 16) {
    float4 av = *(const float4*)&Wc[(size_t)(m0 + a_m) * 8640 + k0 + a_k4];
    As[a_k4 + 0][a_m] = av.x; As[a_k4 + 1][a_m] = av.y;
    As[a_k4 + 2][a_m] = av.z; As[a_k4 + 3][a_m] = av.w;
    int k = k0 + b_k;
    int c = k / 9; int tap = k - c * 9;
    int ky = tap / 3; int kx = tap - ky * 3;
    const float* xrow = xb + (c * 22 + ky) * 42 + kx;
#pragma unroll
    for (int u = 0; u < 4; ++u) {
      int p = p0 + b_p4 + u;
      float v = 0.f;
      if (p < 800) { int y = p / 40; int x = p - y * 40; v = xrow[y * 42 + x]; }
      Bs[b_k][b_p4 + u] = v;
    }
    __syncthreads();
#pragma unroll
    for (int kk = 0; kk < 16; ++kk) {
      float a[4], bb[4];
      *(float4*)a  = *(const float4*)&As[kk][ty << 2];
      *(float4*)bb = *(const float4*)&Bs[kk][tx << 2];
#pragma unroll
      for (int i = 0; i < 4; ++i)
#pragma unroll
        for (int j = 0; j < 4; ++j) acc[i][j] += a[i] * bb[j];
    }
    __syncthreads();
  }
#pragma unroll
  for (int i = 0; i < 4; ++i) {
    int o = m0 + (ty << 2) + i;
    float bs = bias[o];
#pragma unroll
    for (int j = 0; j < 4; ++j) {
      int p = p0 + (tx << 2) + j;
      if (p < 800) T[((size_t)b * 960 + o) * 800 + p] = fmaxf(acc[i][j] + bs, 0.f);
    }
  }
}

// ---------------- RPN heads: obj (12) + reg (48) per pixel ------------------
__global__ __launch_bounds__(256) void rpn_head(const float* __restrict__ t,
                                                const float* __restrict__ cls_w,
                                                const float* __restrict__ cls_b,
                                                const float* __restrict__ reg_w,
                                                const float* __restrict__ reg_b,
                                                float* __restrict__ obj,
                                                float* __restrict__ dlt)
{
  int bp = blockIdx.x;
  int b = bp / 800, p = bp - (bp / 800) * 800;
  __shared__ float tv[960];
  for (int c = threadIdx.x; c < 960; c += 256)
    tv[c] = t[((size_t)b * 960 + c) * 800 + p];
  __syncthreads();
  __shared__ float part[60][4];
  int j = threadIdx.x >> 2, pp = threadIdx.x & 3;
  if (j < 60) {
    const float* wrow = (j < 12) ? &cls_w[j * 960] : &reg_w[(j - 12) * 960];
    float acc = 0.f;
    for (int c = pp; c < 960; c += 4) acc += tv[c] * wrow[c];
    part[j][pp] = acc;
  }
  __syncthreads();
  if (threadIdx.x < 60) {
    int j2 = threadIdx.x;
    float s = part[j2][0] + part[j2][1] + part[j2][2] + part[j2][3];
    if (j2 < 12) {
      obj[(size_t)b * 9600 + p * 12 + j2] = s + cls_b[j2];
    } else {
      int o = j2 - 12;
      dlt[((size_t)b * 9600 + p * 12 + (o >> 2)) * 4 + (o & 3)] = s + reg_b[o];
    }
  }
}

// ---------------- top-k: bitonic sort of packed (score,~idx) keys -----------
__device__ inline unsigned long long pack_key(float v, int g)
{
  unsigned u = __float_as_uint(v);
  u = (u & 0x80000000u) ? ~u : (u | 0x80000000u);
  return ((unsigned long long)u << 32) | (unsigned)(~g);
}

__global__ __launch_bounds__(512) void sort8k(const float* __restrict__ obj,
                                              unsigned long long* __restrict__ topkeys)
{
  __shared__ unsigned long long keys[8192];
  int b = blockIdx.x >> 1, h = blockIdx.x & 1;
  int tid = threadIdx.x;
  for (int i = tid; i < 8192; i += 512) {
    int g = h * 8192 + i;
    unsigned long long key = 0ULL;
    if (g < 9600) key = pack_key(obj[(size_t)b * 9600 + g], g);
    keys[i] = key;
  }
  __syncthreads();
  for (int k = 2; k <= 8192; k <<= 1)
    for (int j = k >> 1; j > 0; j >>= 1) {
      for (int i = tid; i < 8192; i += 512) {
        int ixj = i ^ j;
        if (ixj > i) {
          bool desc = ((i & k) == 0);
          unsigned long long a = keys[i], c = keys[ixj];
          if ((a < c) == desc) { keys[i] = c; keys[ixj] = a; }
        }
      }
      __syncthreads();
    }
  for (int i = tid; i < 1024; i += 512)
    topkeys[(size_t)blockIdx.x * 1024 + i] = keys[i];
}

__global__ __launch_bounds__(256) void merge2k(const unsigned long long* __restrict__ topkeys,
                                               int* __restrict__ selidx)
{
  __shared__ unsigned long long keys[2048];
  int b = blockIdx.x, tid = threadIdx.x;
  for (int i = tid; i < 2048; i += 256) keys[i] = topkeys[(size_t)b * 2048 + i];
  __syncthreads();
  for (int k = 2; k <= 2048; k <<= 1)
    for (int j = k >> 1; j > 0; j >>= 1) {
      for (int i = tid; i < 2048; i += 256) {
        int ixj = i ^ j;
        if (ixj > i) {
          bool desc = ((i & k) == 0);
          unsigned long long a = keys[i], c = keys[ixj];
          if ((a < c) == desc) { keys[i] = c; keys[ixj] = a; }
        }
      }
      __syncthreads();
    }
  for (int i = tid; i < 1000; i += 256)
    selidx[b * 1000 + i] = (int)(~(unsigned)(keys[i] & 0xffffffffULL));
}

// ---------------- decode + clip boxes (ref-exact op order) ------------------
__global__ __launch_bounds__(256) void decode_kernel(const int* __restrict__ selidx,
                                                     const float* __restrict__ dlt,
                                                     float* __restrict__ boxes)
{
#pragma clang fp contract(off)
  int t = blockIdx.x * 256 + threadIdx.x;
  if (t >= 2000) return;
  int b = t / 1000;
  int g = selidx[t];
  int cell = g / 12, a = g - cell * 12;
  int y = cell / 40, x = cell - y * 40;
  int ridx = a >> 2, sidx = a & 3;
  const float sizes_[4]  = {32.f, 64.f, 128.f, 256.f};
  const float ratios_[3] = {0.5f, 1.f, 2.f};
  float size = sizes_[sidx];
  float hr = sqrtf(ratios_[ridx]);
  float wr = 1.f / hr;
  float wsz = wr * size, hsz = hr * size;
  float hw = 0.5f * wsz, hh = 0.5f * hsz;
  float gx = (float)x * 16.f, gy = (float)y * 16.f;
  // emulate reference: anchor corners then reconstructed w/cx (fp32 rounding)
  float a0 = gx - hw, a1 = gy - hh, a2 = gx + hw, a3 = gy + hh;
  float wa = a2 - a0, ha = a3 - a1;
  float cxa = a0 + 0.5f * wa, cya = a1 + 0.5f * ha;
  const float* d = &dlt[(size_t)(b * 9600 + g) * 4];
  float dx = d[0], dy = d[1];
  float dw = fminf(d[2], 4.135166556742356f);
  float dh = fminf(d[3], 4.135166556742356f);
  float cx = dx * wa + cxa;
  float cy = dy * ha + cya;
  float w = expf(dw) * wa;
  float h = expf(dh) * ha;
  float x1 = cx - 0.5f * w, y1 = cy - 0.5f * h;
  float x2 = cx + 0.5f * w, y2 = cy + 0.5f * h;
  x1 = fminf(fmaxf(x1, 0.f), 640.f);
  y1 = fminf(fmaxf(y1, 0.f), 320.f);
  x2 = fminf(fmaxf(x2, 0.f), 640.f);
  y2 = fminf(fmaxf(y2, 0.f), 320.f);
  *(float4*)&boxes[(size_t)t * 4] = make_float4(x1, y1, x2, y2);
}

// ---------------- IoU suppression bit-matrix (j > i, iou > 0.7) -------------
__global__ __launch_bounds__(256) void iou_kernel(const float* __restrict__ boxes,
                                                  unsigned long long* __restrict__ bitrow)
{
#pragma clang fp contract(off)
  int b = blockIdx.y;
  int i = blockIdx.x * 16 + (threadIdx.x >> 4);
  int w = threadIdx.x & 15;
  __shared__ float4 bx[1000];
  for (int t = threadIdx.x; t < 1000; t += 256)
    bx[t] = *(const float4*)&boxes[(size_t)(b * 1000 + t) * 4];
  __syncthreads();
  if (i >= 1000) return;
  float4 bi = bx[i];
  float area_i = (bi.z - bi.x) * (bi.w - bi.y);
  unsigned long long bits = 0ULL;
  for (int t = 0; t < 64; ++t) {
    int j = w * 64 + t;
    if (j > i && j < 1000) {
      float4 bj = bx[j];
      float xx1 = fmaxf(bi.x, bj.x), yy1 = fmaxf(bi.y, bj.y);
      float xx2 = fminf(bi.z, bj.z), yy2 = fminf(bi.w, bj.w);
      float iw = fmaxf(xx2 - xx1, 0.f), ih = fmaxf(yy2 - yy1, 0.f);
      float inter = iw * ih;
      float area_j = (bj.z - bj.x) * (bj.w - bj.y);
      float iou = inter / (area_i + area_j - inter + 1e-6f);
      if (iou > 0.7f) bits |= 1ULL << t;
    }
  }
  bitrow[(size_t)(b * 1000 + i) * 16 + w] = bits;
}

// ---------------- sequential NMS scan + keep-500 + gather props -------------
__device__ inline unsigned long long shfl64(unsigned long long v, int src)
{
  int lo = __shfl((int)(unsigned)(v & 0xffffffffULL), src, 64);
  int hi = __shfl((int)(unsigned)(v >> 32), src, 64);
  return ((unsigned long long)(unsigned)hi << 32) | (unsigned)lo;
}

__global__ __launch_bounds__(64) void nms_scan(const unsigned long long* __restrict__ bitrow,
                                               const float* __restrict__ boxes,
                                               float* __restrict__ props)
{
  int b = blockIdx.x;
  int lane = threadIdx.x;
  unsigned long long alive = 0ULL;
  if (lane < 15) alive = ~0ULL;
  else if (lane == 15) alive = (1ULL << 40) - 1ULL;  // boxes 960..999
  const unsigned long long* rows = bitrow + (size_t)b * 16000;
  for (int i0 = 0; i0 < 1000; i0 += 4) {
    unsigned long long v = rows[i0 * 16 + lane];  // rows i0..i0+3, 16 words each
#pragma unroll
    for (int s = 0; s < 4; ++s) {
      int i = i0 + s;
      unsigned long long row = shfl64(v, (s << 4) | (lane & 15));
      unsigned long long ow = shfl64(alive, i >> 6);
      if ((ow >> (i & 63)) & 1ULL) alive &= ~row;
    }
  }
  __shared__ unsigned long long am[16];
  __shared__ int keep[500];
  if (lane < 16) am[lane] = alive;
  __syncthreads();
  if (lane == 0) {
    int cnt = 0;
    for (int i = 0; i < 1000 && cnt < 500; ++i)
      if ((am[i >> 6] >> (i & 63)) & 1ULL) keep[cnt++] = i;
    for (int i = 0; i < 1000 && cnt < 500; ++i)
      if (!((am[i >> 6] >> (i & 63)) & 1ULL)) keep[cnt++] = i;
  }
  __syncthreads();
  for (int r = lane; r < 500; r += 64) {
    int g = keep[r];
    *(float4*)&props[(size_t)(b * 500 + r) * 4] =
        *(const float4*)&boxes[(size_t)(b * 1000 + g) * 4];
  }
}

// ---------------- transpose features to (b, p, c) for channel-coalesced ROI -
__global__ __launch_bounds__(256) void transpose_feat(const float* __restrict__ f,
                                                      float* __restrict__ ft)
{
  __shared__ float tile[32][33];
  int b = blockIdx.z;
  int c0 = blockIdx.y * 32, p0 = blockIdx.x * 32;
  int tx = threadIdx.x, ty = threadIdx.y;  // (32,8)
  for (int r = ty; r < 32; r += 8)
    tile[r][tx] = f[((size_t)b * 960 + c0 + r) * 800 + p0 + tx];
  __syncthreads();
  for (int r = ty; r < 32; r += 8)
    ft[((size_t)b * 800 + p0 + r) * 960 + c0 + tx] = tile[tx][r];
}

// ---------------- ROI align -> pooled, channel-contiguous (k' = q*960 + c) --
__global__ __launch_bounds__(256) void roi_kernel(const float* __restrict__ ft,
                                                  const float* __restrict__ props,
                                                  float* __restrict__ pooled)
{
  int q = blockIdx.x;    // 0..48
  int nr = blockIdx.y;   // 0..999 (b*500 + r)
  int b = nr / 500;
  int py = q / 7, px = q - py * 7;
  float4 bx = *(const float4*)&props[(size_t)nr * 4];
  float x1 = bx.x / 16.f, y1 = bx.y / 16.f, x2 = bx.z / 16.f, y2 = bx.w / 16.f;
  float rw = fmaxf(x2 - x1, 1.f), rh = fmaxf(y2 - y1, 1.f);
  float bw = rw / 7.f, bh = rh / 7.f;
  int offs[16]; float wts[16];
#pragma unroll
  for (int s = 0; s < 4; ++s) {
    int sy = s >> 1, sx = s & 1;
    float ys = y1 + ((float)py + (sy ? 0.75f : 0.25f)) * bh;
    float xs = x1 + ((float)px + (sx ? 0.75f : 0.25f)) * bw;
    ys = fminf(fmaxf(ys, 0.f), 19.f);
    xs = fminf(fmaxf(xs, 0.f), 39.f);
    int y0 = (int)floorf(ys), x0 = (int)floorf(xs);
    int y1i = y0 + 1 < 19 ? y0 + 1 : 19;
    int x1i = x0 + 1 < 39 ? x0 + 1 : 39;
    float wy = ys - (float)y0, wx = xs - (float)x0;
    int base0 = y0 * 40, base1 = y1i * 40;
    offs[s * 4 + 0] = base0 + x0;  wts[s * 4 + 0] = 0.25f * (1.f - wy) * (1.f - wx);
    offs[s * 4 + 1] = base0 + x1i; wts[s * 4 + 1] = 0.25f * (1.f - wy) * wx;
    offs[s * 4 + 2] = base1 + x0;  wts[s * 4 + 2] = 0.25f * wy * (1.f - wx);
    offs[s * 4 + 3] = base1 + x1i; wts[s * 4 + 3] = 0.25f * wy * wx;
  }
  const float* fb = ft + (size_t)b * 800 * 960;
  float* outp = pooled + (size_t)nr * 47040 + q * 960;
  for (int c = threadIdx.x; c < 960; c += 256) {
    float acc = 0.f;
#pragma unroll
    for (int s = 0; s < 16; ++s) acc += wts[s] * fb[(size_t)offs[s] * 960 + c];
    outp[c] = acc;
  }
}

// ---------------- tiled SGEMM: Y = relu(X @ W + bias) -----------------------
// X: M x K row-major.  W: K x N row-major, row index optionally permuted
// (PERM: GEMM k' -> W row (k'%960)*49 + k'/960, matching pooled's k'=q*960+c).
template <bool PERM>
__global__ __launch_bounds__(256) void sgemm_kernel(const float* __restrict__ X,
                                                    const float* __restrict__ W,
                                                    const float* __restrict__ bias,
                                                    float* __restrict__ Y,
                                                    int M, int N, int K, int relu)
{
  __shared__ float As[16][64];
  __shared__ float Bs[16][64];
  int tid = threadIdx.x;
  int n0 = blockIdx.x * 64, m0 = blockIdx.y * 64;
  int ty = tid >> 4, tx = tid & 15;
  int a_m = tid >> 2, a_k4 = (tid & 3) << 2;
  int b_k = tid >> 4, b_n4 = (tid & 15) << 2;
  float acc[4][4] = {};
  for (int k0 = 0; k0 < K; k0 += 16) {
    int am = m0 + a_m;
    float4 av = make_float4(0.f, 0.f, 0.f, 0.f);
    if (am < M) av = *(const float4*)&X[(size_t)am * K + k0 + a_k4];
    As[a_k4 + 0][a_m] = av.x; As[a_k4 + 1][a_m] = av.y;
    As[a_k4 + 2][a_m] = av.z; As[a_k4 + 3][a_m] = av.w;
    int k = k0 + b_k;
    int wrow;
    if (PERM) { int c = k % 960; int qq = k / 960; wrow = c * 49 + qq; }
    else wrow = k;
    *(float4*)&Bs[b_k][b_n4] = *(const float4*)&W[(size_t)wrow * N + n0 + b_n4];
    __syncthreads();
#pragma unroll
    for (int kk = 0; kk < 16; ++kk) {
      float a[4], bb[4];
      *(float4*)a  = *(const float4*)&As[kk][ty << 2];
      *(float4*)bb = *(const float4*)&Bs[kk][tx << 2];
#pragma unroll
      for (int i = 0; i < 4; ++i)
#pragma unroll
        for (int j = 0; j < 4; ++j) acc[i][j] += a[i] * bb[j];
    }
    __syncthreads();
  }
#pragma unroll
  for (int i = 0; i < 4; ++i) {
    int m = m0 + (ty << 2) + i;
    if (m < M) {
      int n = n0 + (tx << 2);
      float4 o;
      o.x = acc[i][0] + bias[n + 0];
      o.y = acc[i][1] + bias[n + 1];
      o.z = acc[i][2] + bias[n + 2];
      o.w = acc[i][3] + bias[n + 3];
      if (relu) {
        o.x = fmaxf(o.x, 0.f); o.y = fmaxf(o.y, 0.f);
        o.z = fmaxf(o.z, 0.f); o.w = fmaxf(o.w, 0.f);
      }
      *(float4*)&Y[(size_t)m * N + n] = o;
    }
  }
}

// ---------------- final cls/bbox heads: out (2,500,25) ----------------------
__global__ __launch_bounds__(256) void out_head(const float* __restrict__ x2,
                                                const float* __restrict__ cls_w,
                                                const float* __restrict__ cls_b,
                                                const float* __restrict__ bbox_w,
                                                const float* __restrict__ bbox_b,
                                                float* __restrict__ out)
{
  int n = blockIdx.x;
  __shared__ float xv[1024];
  __shared__ float part[25][8];
  for (int k = threadIdx.x; k < 1024; k += 256) xv[k] = x2[(size_t)n * 1024 + k];
  __syncthreads();
  int j = threadIdx.x >> 3, pp = threadIdx.x & 7;
  if (j < 25) {
    float acc = 0.f;
    if (j < 5) {
      for (int k = pp; k < 1024; k += 8) acc += xv[k] * cls_w[k * 5 + j];
    } else {
      int jj = j - 5;
      for (int k = pp; k < 1024; k += 8) acc += xv[k] * bbox_w[k * 20 + jj];
    }
    part[j][pp] = acc;
  }
  __syncthreads();
  if (threadIdx.x < 25) {
    int j2 = threadIdx.x;
    float s = 0.f;
#pragma unroll
    for (int p = 0; p < 8; ++p) s += part[j2][p];
    s += (j2 < 5) ? cls_b[j2] : bbox_b[j2 - 5];
    out[(size_t)n * 25 + j2] = s;
  }
}

// ---------------------------------------------------------------------------
extern "C" void kernel_launch(void* const* d_in, const int* in_sizes, int n_in,
                              void* d_out, int out_size, void* d_ws, size_t ws_size,
                              hipStream_t stream)
{
  const float* features  = (const float*)d_in[0];
  const float* conv_w    = (const float*)d_in[1];
  const float* conv_b    = (const float*)d_in[2];
  const float* rpn_cls_w = (const float*)d_in[3];
  const float* rpn_cls_b = (const float*)d_in[4];
  const float* rpn_reg_w = (const float*)d_in[5];
  const float* rpn_reg_b = (const float*)d_in[6];
  const float* fc6_w     = (const float*)d_in[7];
  const float* fc6_b     = (const float*)d_in[8];
  const float* fc7_w     = (const float*)d_in[9];
  const float* fc7_b     = (const float*)d_in[10];
  const float* hd_cls_w  = (const float*)d_in[11];
  const float* hd_cls_b  = (const float*)d_in[12];
  const float* hd_bbox_w = (const float*)d_in[13];
  const float* hd_bbox_b = (const float*)d_in[14];

  char* ws = (char*)d_ws;
  size_t off = 0;
  auto alloc = [&](size_t bytes) -> char* {
    char* p = ws + off;
    off += (bytes + 255) & ~(size_t)255;
    return p;
  };
  float* xpad   = (float*)alloc(2ull * 960 * 22 * 42 * 4);
  float* t      = (float*)alloc(2ull * 960 * 800 * 4);
  float* obj    = (float*)alloc(2ull * 9600 * 4);
  float* dlt    = (float*)alloc(2ull * 9600 * 4 * 4);
  unsigned long long* topkeys = (unsigned long long*)alloc(4ull * 1024 * 8);
  int* selidx   = (int*)alloc(2000ull * 4);
  float* boxes  = (float*)alloc(2ull * 1000 * 4 * 4);
  unsigned long long* bitrow = (unsigned long long*)alloc(2ull * 1000 * 16 * 8);
  float* props  = (float*)alloc(2ull * 500 * 4 * 4);
  float* featT  = (float*)alloc(2ull * 800 * 960 * 4);
  float* pooled = (float*)alloc(1000ull * 47040 * 4);
  float* x1buf  = (float*)alloc(1000ull * 1024 * 4);
  float* x2buf  = (float*)alloc(1000ull * 1024 * 4);

  pad_kernel<<<(2 * 960 * 22 * 42 + 255) / 256, 256, 0, stream>>>(features, xpad);
  conv_kernel<<<dim3(13, 15, 2), 256, 0, stream>>>(conv_w, xpad, conv_b, t);
  rpn_head<<<1600, 256, 0, stream>>>(t, rpn_cls_w, rpn_cls_b, rpn_reg_w, rpn_reg_b, obj, dlt);
  sort8k<<<4, 512, 0, stream>>>(obj, topkeys);
  merge2k<<<2, 256, 0, stream>>>(topkeys, selidx);
  decode_kernel<<<8, 256, 0, stream>>>(selidx, dlt, boxes);
  iou_kernel<<<dim3(63, 2), 256, 0, stream>>>(boxes, bitrow);
  nms_scan<<<2, 64, 0, stream>>>(bitrow, boxes, props);
  transpose_feat<<<dim3(25, 30, 2), dim3(32, 8), 0, stream>>>(features, featT);
  roi_kernel<<<dim3(49, 1000), 256, 0, stream>>>(featT, props, pooled);
  sgemm_kernel<true><<<dim3(16, 16), 256, 0, stream>>>(pooled, fc6_w, fc6_b, x1buf,
                                                       1000, 1024, 47040, 1);
  sgemm_kernel<false><<<dim3(16, 16), 256, 0, stream>>>(x1buf, fc7_w, fc7_b, x2buf,
                                                        1000, 1024, 1024, 1);
  out_head<<<1000, 256, 0, stream>>>(x2buf, hd_cls_w, hd_cls_b, hd_bbox_w, hd_bbox_b,
                                     (float*)d_out);
}

// Round 2
// 2024.224 us; speedup vs baseline: 2.4710x; 2.4710x over previous
//
#include <hip/hip_runtime.h>
#include <hip/hip_bf16.h>
#include <cstdint>
#include <cstddef>

// ---------------------------------------------------------------------------
// Vehicle detection pipeline (RPN conv -> heads -> topk -> NMS -> ROI -> FC)
// B=2, C=960, H=20, W=40, A=12, PRE=1000, POST=500, POOL=7.
// FC6/FC7 run as bf16 MFMA GEMMs (post-selection, tolerance-safe).
// ---------------------------------------------------------------------------

typedef __attribute__((ext_vector_type(8))) short short8;
typedef __attribute__((ext_vector_type(4))) float f32x4;

__device__ __forceinline__ void gld_lds16(const void* g, void* l)
{
  __builtin_amdgcn_global_load_lds(
      (const __attribute__((address_space(1))) unsigned int*)g,
      (__attribute__((address_space(3))) unsigned int*)l, 16, 0, 0);
}

// ---------------- pad input for 3x3 SAME conv: (2,960,22,42) ----------------
__global__ __launch_bounds__(256) void pad_kernel(const float* __restrict__ f,
                                                  float* __restrict__ xp)
{
  int idx = blockIdx.x * 256 + threadIdx.x;
  const int total = 2 * 960 * 22 * 42;
  if (idx >= total) return;
  int xx = idx % 42;
  int r  = idx / 42;
  int yy = r % 22;
  int bc = r / 22;
  float v = 0.f;
  if (yy >= 1 && yy <= 20 && xx >= 1 && xx <= 40)
    v = f[bc * 800 + (yy - 1) * 40 + (xx - 1)];
  xp[idx] = v;
}

// ---------------- conv 3x3 as implicit GEMM: M=960(o), N=800(p), K=8640 -----
__global__ __launch_bounds__(256) void conv_kernel(const float* __restrict__ Wc,
                                                   const float* __restrict__ Xpad,
                                                   const float* __restrict__ bias,
                                                   float* __restrict__ T)
{
  __shared__ float As[16][64];
  __shared__ float Bs[16][64];
  int tid = threadIdx.x;
  int b  = blockIdx.z;
  int p0 = blockIdx.x * 64;
  int m0 = blockIdx.y * 64;
  int ty = tid >> 4, tx = tid & 15;
  int a_m = tid >> 2, a_k4 = (tid & 3) << 2;
  int b_k = tid >> 4, b_p4 = (tid & 15) << 2;
  const float* xb = Xpad + (size_t)b * 960 * 22 * 42;
  float acc[4][4] = {};
  for (int k0 = 0; k0 < 8640; k0 += 16) {
    float4 av = *(const float4*)&Wc[(size_t)(m0 + a_m) * 8640 + k0 + a_k4];
    As[a_k4 + 0][a_m] = av.x; As[a_k4 + 1][a_m] = av.y;
    As[a_k4 + 2][a_m] = av.z; As[a_k4 + 3][a_m] = av.w;
    int k = k0 + b_k;
    int c = k / 9; int tap = k - c * 9;
    int ky = tap / 3; int kx = tap - ky * 3;
    const float* xrow = xb + (c * 22 + ky) * 42 + kx;
#pragma unroll
    for (int u = 0; u < 4; ++u) {
      int p = p0 + b_p4 + u;
      float v = 0.f;
      if (p < 800) { int y = p / 40; int x = p - y * 40; v = xrow[y * 42 + x]; }
      Bs[b_k][b_p4 + u] = v;
    }
    __syncthreads();
#pragma unroll
    for (int kk = 0; kk < 16; ++kk) {
      float a[4], bb[4];
      *(float4*)a  = *(const float4*)&As[kk][ty << 2];
      *(float4*)bb = *(const float4*)&Bs[kk][tx << 2];
#pragma unroll
      for (int i = 0; i < 4; ++i)
#pragma unroll
        for (int j = 0; j < 4; ++j) acc[i][j] += a[i] * bb[j];
    }
    __syncthreads();
  }
#pragma unroll
  for (int i = 0; i < 4; ++i) {
    int o = m0 + (ty << 2) + i;
    float bs = bias[o];
#pragma unroll
    for (int j = 0; j < 4; ++j) {
      int p = p0 + (tx << 2) + j;
      if (p < 800) T[((size_t)b * 960 + o) * 800 + p] = fmaxf(acc[i][j] + bs, 0.f);
    }
  }
}

// ---------------- RPN heads: obj (12) + reg (48) per pixel ------------------
__global__ __launch_bounds__(256) void rpn_head(const float* __restrict__ t,
                                                const float* __restrict__ cls_w,
                                                const float* __restrict__ cls_b,
                                                const float* __restrict__ reg_w,
                                                const float* __restrict__ reg_b,
                                                float* __restrict__ obj,
                                                float* __restrict__ dlt)
{
  int bp = blockIdx.x;
  int b = bp / 800, p = bp - (bp / 800) * 800;
  __shared__ float tv[960];
  for (int c = threadIdx.x; c < 960; c += 256)
    tv[c] = t[((size_t)b * 960 + c) * 800 + p];
  __syncthreads();
  __shared__ float part[60][4];
  int j = threadIdx.x >> 2, pp = threadIdx.x & 3;
  if (j < 60) {
    const float* wrow = (j < 12) ? &cls_w[j * 960] : &reg_w[(j - 12) * 960];
    float acc = 0.f;
    for (int c = pp; c < 960; c += 4) acc += tv[c] * wrow[c];
    part[j][pp] = acc;
  }
  __syncthreads();
  if (threadIdx.x < 60) {
    int j2 = threadIdx.x;
    float s = part[j2][0] + part[j2][1] + part[j2][2] + part[j2][3];
    if (j2 < 12) {
      obj[(size_t)b * 9600 + p * 12 + j2] = s + cls_b[j2];
    } else {
      int o = j2 - 12;
      dlt[((size_t)b * 9600 + p * 12 + (o >> 2)) * 4 + (o & 3)] = s + reg_b[o];
    }
  }
}

// ---------------- top-k: bitonic sort of packed (score,~idx) keys -----------
__device__ inline unsigned long long pack_key(float v, int g)
{
  unsigned u = __float_as_uint(v);
  u = (u & 0x80000000u) ? ~u : (u | 0x80000000u);
  return ((unsigned long long)u << 32) | (unsigned)(~g);
}

__global__ __launch_bounds__(512) void sort8k(const float* __restrict__ obj,
                                              unsigned long long* __restrict__ topkeys)
{
  __shared__ unsigned long long keys[8192];
  int b = blockIdx.x >> 1, h = blockIdx.x & 1;
  int tid = threadIdx.x;
  for (int i = tid; i < 8192; i += 512) {
    int g = h * 8192 + i;
    unsigned long long key = 0ULL;
    if (g < 9600) key = pack_key(obj[(size_t)b * 9600 + g], g);
    keys[i] = key;
  }
  __syncthreads();
  for (int k = 2; k <= 8192; k <<= 1)
    for (int j = k >> 1; j > 0; j >>= 1) {
      for (int i = tid; i < 8192; i += 512) {
        int ixj = i ^ j;
        if (ixj > i) {
          bool desc = ((i & k) == 0);
          unsigned long long a = keys[i], c = keys[ixj];
          if ((a < c) == desc) { keys[i] = c; keys[ixj] = a; }
        }
      }
      __syncthreads();
    }
  for (int i = tid; i < 1024; i += 512)
    topkeys[(size_t)blockIdx.x * 1024 + i] = keys[i];
}

__global__ __launch_bounds__(256) void merge2k(const unsigned long long* __restrict__ topkeys,
                                               int* __restrict__ selidx)
{
  __shared__ unsigned long long keys[2048];
  int b = blockIdx.x, tid = threadIdx.x;
  for (int i = tid; i < 2048; i += 256) keys[i] = topkeys[(size_t)b * 2048 + i];
  __syncthreads();
  for (int k = 2; k <= 2048; k <<= 1)
    for (int j = k >> 1; j > 0; j >>= 1) {
      for (int i = tid; i < 2048; i += 256) {
        int ixj = i ^ j;
        if (ixj > i) {
          bool desc = ((i & k) == 0);
          unsigned long long a = keys[i], c = keys[ixj];
          if ((a < c) == desc) { keys[i] = c; keys[ixj] = a; }
        }
      }
      __syncthreads();
    }
  for (int i = tid; i < 1000; i += 256)
    selidx[b * 1000 + i] = (int)(~(unsigned)(keys[i] & 0xffffffffULL));
}

// ---------------- decode + clip boxes (ref-exact op order) ------------------
__global__ __launch_bounds__(256) void decode_kernel(const int* __restrict__ selidx,
                                                     const float* __restrict__ dlt,
                                                     float* __restrict__ boxes)
{
#pragma clang fp contract(off)
  int t = blockIdx.x * 256 + threadIdx.x;
  if (t >= 2000) return;
  int b = t / 1000;
  int g = selidx[t];
  int cell = g / 12, a = g - cell * 12;
  int y = cell / 40, x = cell - y * 40;
  int ridx = a >> 2, sidx = a & 3;
  const float sizes_[4]  = {32.f, 64.f, 128.f, 256.f};
  const float ratios_[3] = {0.5f, 1.f, 2.f};
  float size = sizes_[sidx];
  float hr = sqrtf(ratios_[ridx]);
  float wr = 1.f / hr;
  float wsz = wr * size, hsz = hr * size;
  float hw = 0.5f * wsz, hh = 0.5f * hsz;
  float gx = (float)x * 16.f, gy = (float)y * 16.f;
  float a0 = gx - hw, a1 = gy - hh, a2 = gx + hw, a3 = gy + hh;
  float wa = a2 - a0, ha = a3 - a1;
  float cxa = a0 + 0.5f * wa, cya = a1 + 0.5f * ha;
  const float* d = &dlt[(size_t)(b * 9600 + g) * 4];
  float dx = d[0], dy = d[1];
  float dw = fminf(d[2], 4.135166556742356f);
  float dh = fminf(d[3], 4.135166556742356f);
  float cx = dx * wa + cxa;
  float cy = dy * ha + cya;
  float w = expf(dw) * wa;
  float h = expf(dh) * ha;
  float x1 = cx - 0.5f * w, y1 = cy - 0.5f * h;
  float x2 = cx + 0.5f * w, y2 = cy + 0.5f * h;
  x1 = fminf(fmaxf(x1, 0.f), 640.f);
  y1 = fminf(fmaxf(y1, 0.f), 320.f);
  x2 = fminf(fmaxf(x2, 0.f), 640.f);
  y2 = fminf(fmaxf(y2, 0.f), 320.f);
  *(float4*)&boxes[(size_t)t * 4] = make_float4(x1, y1, x2, y2);
}

// ---------------- IoU suppression bit-matrix (j > i, iou > 0.7) -------------
__global__ __launch_bounds__(256) void iou_kernel(const float* __restrict__ boxes,
                                                  unsigned long long* __restrict__ bitrow)
{
#pragma clang fp contract(off)
  int b = blockIdx.y;
  int i = blockIdx.x * 16 + (threadIdx.x >> 4);
  int w = threadIdx.x & 15;
  __shared__ float4 bx[1000];
  for (int t = threadIdx.x; t < 1000; t += 256)
    bx[t] = *(const float4*)&boxes[(size_t)(b * 1000 + t) * 4];
  __syncthreads();
  if (i >= 1000) return;
  float4 bi = bx[i];
  float area_i = (bi.z - bi.x) * (bi.w - bi.y);
  unsigned long long bits = 0ULL;
  for (int t = 0; t < 64; ++t) {
    int j = w * 64 + t;
    if (j > i && j < 1000) {
      float4 bj = bx[j];
      float xx1 = fmaxf(bi.x, bj.x), yy1 = fmaxf(bi.y, bj.y);
      float xx2 = fminf(bi.z, bj.z), yy2 = fminf(bi.w, bj.w);
      float iw = fmaxf(xx2 - xx1, 0.f), ih = fmaxf(yy2 - yy1, 0.f);
      float inter = iw * ih;
      float area_j = (bj.z - bj.x) * (bj.w - bj.y);
      float iou = inter / (area_i + area_j - inter + 1e-6f);
      if (iou > 0.7f) bits |= 1ULL << t;
    }
  }
  bitrow[(size_t)(b * 1000 + i) * 16 + w] = bits;
}

// ---------------- sequential NMS scan + keep-500 + gather props -------------
__device__ inline unsigned long long shfl64(unsigned long long v, int src)
{
  int lo = __shfl((int)(unsigned)(v & 0xffffffffULL), src, 64);
  int hi = __shfl((int)(unsigned)(v >> 32), src, 64);
  return ((unsigned long long)(unsigned)hi << 32) | (unsigned)lo;
}

__global__ __launch_bounds__(64) void nms_scan(const unsigned long long* __restrict__ bitrow,
                                               const float* __restrict__ boxes,
                                               float* __restrict__ props)
{
  int b = blockIdx.x;
  int lane = threadIdx.x;
  unsigned long long alive = 0ULL;
  if (lane < 15) alive = ~0ULL;
  else if (lane == 15) alive = (1ULL << 40) - 1ULL;
  const unsigned long long* rows = bitrow + (size_t)b * 16000;
  for (int i0 = 0; i0 < 1000; i0 += 4) {
    unsigned long long v = rows[i0 * 16 + lane];
#pragma unroll
    for (int s = 0; s < 4; ++s) {
      int i = i0 + s;
      unsigned long long row = shfl64(v, (s << 4) | (lane & 15));
      unsigned long long ow = shfl64(alive, i >> 6);
      if ((ow >> (i & 63)) & 1ULL) alive &= ~row;
    }
  }
  __shared__ unsigned long long am[16];
  __shared__ int keep[500];
  if (lane < 16) am[lane] = alive;
  __syncthreads();
  if (lane == 0) {
    int cnt = 0;
    for (int i = 0; i < 1000 && cnt < 500; ++i)
      if ((am[i >> 6] >> (i & 63)) & 1ULL) keep[cnt++] = i;
    for (int i = 0; i < 1000 && cnt < 500; ++i)
      if (!((am[i >> 6] >> (i & 63)) & 1ULL)) keep[cnt++] = i;
  }
  __syncthreads();
  for (int r = lane; r < 500; r += 64) {
    int g = keep[r];
    *(float4*)&props[(size_t)(b * 500 + r) * 4] =
        *(const float4*)&boxes[(size_t)(b * 1000 + g) * 4];
  }
}

// ---------------- transpose features to (b, p, c) for channel-coalesced ROI -
__global__ __launch_bounds__(256) void transpose_feat(const float* __restrict__ f,
                                                      float* __restrict__ ft)
{
  __shared__ float tile[32][33];
  int b = blockIdx.z;
  int c0 = blockIdx.y * 32, p0 = blockIdx.x * 32;
  int tx = threadIdx.x, ty = threadIdx.y;
  for (int r = ty; r < 32; r += 8)
    tile[r][tx] = f[((size_t)b * 960 + c0 + r) * 800 + p0 + tx];
  __syncthreads();
  for (int r = ty; r < 32; r += 8)
    ft[((size_t)b * 800 + p0 + r) * 960 + c0 + tx] = tile[tx][r];
}

// ---------------- ROI align -> pooled bf16, k' = q*960 + c ------------------
// grid.y = 1024: rows >= 1000 zero-filled (pad rows for the 128-tile GEMM).
__global__ __launch_bounds__(256) void roi_kernel(const float* __restrict__ ft,
                                                  const float* __restrict__ props,
                                                  __hip_bfloat16* __restrict__ pooled)
{
  int q = blockIdx.x;
  int nr = blockIdx.y;
  __hip_bfloat16* outp = pooled + (size_t)nr * 47040 + q * 960;
  if (nr >= 1000) {
    for (int c = threadIdx.x; c < 960; c += 256) outp[c] = __float2bfloat16(0.f);
    return;
  }
  int b = nr / 500;
  int py = q / 7, px = q - py * 7;
  float4 bx = *(const float4*)&props[(size_t)nr * 4];
  float x1 = bx.x / 16.f, y1 = bx.y / 16.f, x2 = bx.z / 16.f, y2 = bx.w / 16.f;
  float rw = fmaxf(x2 - x1, 1.f), rh = fmaxf(y2 - y1, 1.f);
  float bw = rw / 7.f, bh = rh / 7.f;
  int offs[16]; float wts[16];
#pragma unroll
  for (int s = 0; s < 4; ++s) {
    int sy = s >> 1, sx = s & 1;
    float ys = y1 + ((float)py + (sy ? 0.75f : 0.25f)) * bh;
    float xs = x1 + ((float)px + (sx ? 0.75f : 0.25f)) * bw;
    ys = fminf(fmaxf(ys, 0.f), 19.f);
    xs = fminf(fmaxf(xs, 0.f), 39.f);
    int y0 = (int)floorf(ys), x0 = (int)floorf(xs);
    int y1i = y0 + 1 < 19 ? y0 + 1 : 19;
    int x1i = x0 + 1 < 39 ? x0 + 1 : 39;
    float wy = ys - (float)y0, wx = xs - (float)x0;
    int base0 = y0 * 40, base1 = y1i * 40;
    offs[s * 4 + 0] = base0 + x0;  wts[s * 4 + 0] = 0.25f * (1.f - wy) * (1.f - wx);
    offs[s * 4 + 1] = base0 + x1i; wts[s * 4 + 1] = 0.25f * (1.f - wy) * wx;
    offs[s * 4 + 2] = base1 + x0;  wts[s * 4 + 2] = 0.25f * wy * (1.f - wx);
    offs[s * 4 + 3] = base1 + x1i; wts[s * 4 + 3] = 0.25f * wy * wx;
  }
  const float* fb = ft + (size_t)b * 800 * 960;
  for (int c = threadIdx.x; c < 960; c += 256) {
    float acc = 0.f;
#pragma unroll
    for (int s = 0; s < 16; ++s) acc += wts[s] * fb[(size_t)offs[s] * 960 + c];
    outp[c] = __float2bfloat16(acc);
  }
}

// ---------------- transpose-cast fc6_w -> WbT bf16 [n=1024][k=47040] --------
// GEMM k = q*960 + c maps to fc6_w row c*49 + q.
__global__ __launch_bounds__(256) void cast_w6(const float* __restrict__ w6,
                                               __hip_bfloat16* __restrict__ WbT)
{
  __shared__ float tile[32][33];
  int c0 = blockIdx.x * 32;   // 30
  int n0 = blockIdx.y * 32;   // 32
  int q  = blockIdx.z;        // 49
  int tx = threadIdx.x & 31, ty = threadIdx.x >> 5;  // (32,8)
  for (int rr = ty; rr < 32; rr += 8)
    tile[rr][tx] = w6[((size_t)(c0 + rr) * 49 + q) * 1024 + n0 + tx];
  __syncthreads();
  for (int rr = ty; rr < 32; rr += 8)
    WbT[(size_t)(n0 + rr) * 47040 + q * 960 + c0 + tx] = __float2bfloat16(tile[tx][rr]);
}

// ---------------- transpose-cast fc7_w -> fc7T bf16 [n=1024][k=1024] --------
__global__ __launch_bounds__(256) void cast_w7(const float* __restrict__ w7,
                                               __hip_bfloat16* __restrict__ WT)
{
  __shared__ float tile[32][33];
  int k0 = blockIdx.x * 32, n0 = blockIdx.y * 32;
  int tx = threadIdx.x & 31, ty = threadIdx.x >> 5;
  for (int rr = ty; rr < 32; rr += 8)
    tile[rr][tx] = w7[(size_t)(k0 + rr) * 1024 + n0 + tx];
  __syncthreads();
  for (int rr = ty; rr < 32; rr += 8)
    WT[(size_t)(n0 + rr) * 1024 + k0 + tx] = __float2bfloat16(tile[tx][rr]);
}

// ---------------- bf16 MFMA GEMM: C(+)= A(M=1024 x K) * BT(N=1024 x K)^T ----
// 128x128 tile, BK=32, 16x16x32 bf16 MFMA, global_load_lds(16B) staging,
// split-K over grid.z with fp32 atomicAdd epilogue (C must be pre-zeroed).
__global__ __launch_bounds__(256, 2) void gemm_bf16(const ushort* __restrict__ A,
                                                    const ushort* __restrict__ BT,
                                                    float* __restrict__ C,
                                                    int Klen, int ksteps, int splitk)
{
  __shared__ __align__(16) ushort As[128 * 32];
  __shared__ __align__(16) ushort Bs[128 * 32];
  int tid = threadIdx.x;
  int wave = tid >> 6, lane = tid & 63;
  int n0 = blockIdx.x * 128, m0 = blockIdx.y * 128;
  int steps_per = (ksteps + splitk - 1) / splitk;
  int s0 = blockIdx.z * steps_per;
  int s1 = min(ksteps, s0 + steps_per);

  // staging: each wave stages 2x16 rows of A and of B; lane l covers
  // row = base + l/4, k-chunk (l%4)*8 -> LDS dest base + l*16B (contiguous).
  const ushort* Ap0 = A  + (size_t)(m0 + wave * 32 + (lane >> 2)) * Klen + ((lane & 3) << 3);
  const ushort* Bp0 = BT + (size_t)(n0 + wave * 32 + (lane >> 2)) * Klen + ((lane & 3) << 3);
  size_t rstep = (size_t)16 * Klen;
  ushort* Al0 = &As[(wave * 32) * 32];
  ushort* Al1 = &As[(wave * 32 + 16) * 32];
  ushort* Bl0 = &Bs[(wave * 32) * 32];
  ushort* Bl1 = &Bs[(wave * 32 + 16) * 32];

  // compute: wave quadrant (wm, wn) of 64x64, 4x4 MFMA tiles of 16x16x32
  int wm = (wave >> 1) * 64, wn = (wave & 1) * 64;
  int ar = lane & 15, aq = (lane >> 4) << 3;
  f32x4 acc[4][4] = {};

  for (int s = s0; s < s1; ++s) {
    size_t k0 = (size_t)s << 5;
    gld_lds16(Ap0 + k0, Al0);
    gld_lds16(Ap0 + rstep + k0, Al1);
    gld_lds16(Bp0 + k0, Bl0);
    gld_lds16(Bp0 + rstep + k0, Bl1);
    __syncthreads();
    short8 af[4], bfv[4];
#pragma unroll
    for (int mi = 0; mi < 4; ++mi)
      af[mi] = *(const short8*)&As[(wm + mi * 16 + ar) * 32 + aq];
#pragma unroll
    for (int ni = 0; ni < 4; ++ni)
      bfv[ni] = *(const short8*)&Bs[(wn + ni * 16 + ar) * 32 + aq];
#pragma unroll
    for (int mi = 0; mi < 4; ++mi)
#pragma unroll
      for (int ni = 0; ni < 4; ++ni)
        acc[mi][ni] = __builtin_amdgcn_mfma_f32_16x16x32_bf16(af[mi], bfv[ni],
                                                              acc[mi][ni], 0, 0, 0);
    __syncthreads();
  }
  // C/D layout: col = lane&15, row = (lane>>4)*4 + reg  [m89-verified]
  int crow = m0 + wm + ((lane >> 4) << 2);
  int ccol = n0 + wn + (lane & 15);
#pragma unroll
  for (int mi = 0; mi < 4; ++mi)
#pragma unroll
    for (int ni = 0; ni < 4; ++ni) {
      float* cp = &C[(size_t)(crow + mi * 16) * 1024 + ccol + ni * 16];
      f32x4 v = acc[mi][ni];
      atomicAdd(cp,        v.x);
      atomicAdd(cp + 1024, v.y);
      atomicAdd(cp + 2048, v.z);
      atomicAdd(cp + 3072, v.w);
    }
}

// ---------------- epilogues: bias + relu (+cast) ----------------------------
__global__ __launch_bounds__(256) void ep_bf16(const float* __restrict__ Cacc,
                                               const float* __restrict__ bias,
                                               __hip_bfloat16* __restrict__ out)
{
  int idx = blockIdx.x * 256 + threadIdx.x;
  out[idx] = __float2bfloat16(fmaxf(Cacc[idx] + bias[idx & 1023], 0.f));
}

__global__ __launch_bounds__(256) void ep_f32(const float* __restrict__ Cacc,
                                              const float* __restrict__ bias,
                                              float* __restrict__ out)
{
  int idx = blockIdx.x * 256 + threadIdx.x;
  out[idx] = fmaxf(Cacc[idx] + bias[idx & 1023], 0.f);
}

// ---------------- final cls/bbox heads: out (2,500,25) ----------------------
__global__ __launch_bounds__(256) void out_head(const float* __restrict__ x2,
                                                const float* __restrict__ cls_w,
                                                const float* __restrict__ cls_b,
                                                const float* __restrict__ bbox_w,
                                                const float* __restrict__ bbox_b,
                                                float* __restrict__ out)
{
  int n = blockIdx.x;
  __shared__ float xv[1024];
  __shared__ float part[25][8];
  for (int k = threadIdx.x; k < 1024; k += 256) xv[k] = x2[(size_t)n * 1024 + k];
  __syncthreads();
  int j = threadIdx.x >> 3, pp = threadIdx.x & 7;
  if (j < 25) {
    float acc = 0.f;
    if (j < 5) {
      for (int k = pp; k < 1024; k += 8) acc += xv[k] * cls_w[k * 5 + j];
    } else {
      int jj = j - 5;
      for (int k = pp; k < 1024; k += 8) acc += xv[k] * bbox_w[k * 20 + jj];
    }
    part[j][pp] = acc;
  }
  __syncthreads();
  if (threadIdx.x < 25) {
    int j2 = threadIdx.x;
    float s = 0.f;
#pragma unroll
    for (int p = 0; p < 8; ++p) s += part[j2][p];
    s += (j2 < 5) ? cls_b[j2] : bbox_b[j2 - 5];
    out[(size_t)n * 25 + j2] = s;
  }
}

// ---------------------------------------------------------------------------
extern "C" void kernel_launch(void* const* d_in, const int* in_sizes, int n_in,
                              void* d_out, int out_size, void* d_ws, size_t ws_size,
                              hipStream_t stream)
{
  const float* features  = (const float*)d_in[0];
  const float* conv_w    = (const float*)d_in[1];
  const float* conv_b    = (const float*)d_in[2];
  const float* rpn_cls_w = (const float*)d_in[3];
  const float* rpn_cls_b = (const float*)d_in[4];
  const float* rpn_reg_w = (const float*)d_in[5];
  const float* rpn_reg_b = (const float*)d_in[6];
  const float* fc6_w     = (const float*)d_in[7];
  const float* fc6_b     = (const float*)d_in[8];
  const float* fc7_w     = (const float*)d_in[9];
  const float* fc7_b     = (const float*)d_in[10];
  const float* hd_cls_w  = (const float*)d_in[11];
  const float* hd_cls_b  = (const float*)d_in[12];
  const float* hd_bbox_w = (const float*)d_in[13];
  const float* hd_bbox_b = (const float*)d_in[14];

  char* ws = (char*)d_ws;
  size_t off = 0;
  auto alloc = [&](size_t bytes) -> char* {
    char* p = ws + off;
    off += (bytes + 255) & ~(size_t)255;
    return p;
  };
  float* xpad   = (float*)alloc(2ull * 960 * 22 * 42 * 4);
  float* t      = (float*)alloc(2ull * 960 * 800 * 4);
  float* obj    = (float*)alloc(2ull * 9600 * 4);
  float* dlt    = (float*)alloc(2ull * 9600 * 4 * 4);
  unsigned long long* topkeys = (unsigned long long*)alloc(4ull * 1024 * 8);
  int* selidx   = (int*)alloc(2000ull * 4);
  float* boxes  = (float*)alloc(2ull * 1000 * 4 * 4);
  unsigned long long* bitrow = (unsigned long long*)alloc(2ull * 1000 * 16 * 8);
  float* props  = (float*)alloc(2ull * 500 * 4 * 4);
  float* featT  = (float*)alloc(2ull * 800 * 960 * 4);
  __hip_bfloat16* pooled = (__hip_bfloat16*)alloc(1024ull * 47040 * 2);
  __hip_bfloat16* WbT    = (__hip_bfloat16*)alloc(1024ull * 47040 * 2);
  __hip_bfloat16* fc7T   = (__hip_bfloat16*)alloc(1024ull * 1024 * 2);
  float* Cacc   = (float*)alloc(1024ull * 1024 * 4);
  float* Cacc2  = (float*)alloc(1024ull * 1024 * 4);
  __hip_bfloat16* x1bf = (__hip_bfloat16*)alloc(1024ull * 1024 * 2);
  float* x2buf  = (float*)alloc(1024ull * 1024 * 4);

  hipMemsetAsync(Cacc, 0, 1024ull * 1024 * 4, stream);
  hipMemsetAsync(Cacc2, 0, 1024ull * 1024 * 4, stream);

  pad_kernel<<<(2 * 960 * 22 * 42 + 255) / 256, 256, 0, stream>>>(features, xpad);
  conv_kernel<<<dim3(13, 15, 2), 256, 0, stream>>>(conv_w, xpad, conv_b, t);
  rpn_head<<<1600, 256, 0, stream>>>(t, rpn_cls_w, rpn_cls_b, rpn_reg_w, rpn_reg_b, obj, dlt);
  sort8k<<<4, 512, 0, stream>>>(obj, topkeys);
  merge2k<<<2, 256, 0, stream>>>(topkeys, selidx);
  decode_kernel<<<8, 256, 0, stream>>>(selidx, dlt, boxes);
  iou_kernel<<<dim3(63, 2), 256, 0, stream>>>(boxes, bitrow);
  nms_scan<<<2, 64, 0, stream>>>(bitrow, boxes, props);
  transpose_feat<<<dim3(25, 30, 2), dim3(32, 8), 0, stream>>>(features, featT);
  roi_kernel<<<dim3(49, 1024), 256, 0, stream>>>(featT, props, pooled);
  cast_w6<<<dim3(30, 32, 49), 256, 0, stream>>>(fc6_w, WbT);
  cast_w7<<<dim3(32, 32), 256, 0, stream>>>(fc7_w, fc7T);
  gemm_bf16<<<dim3(8, 8, 8), 256, 0, stream>>>((const ushort*)pooled, (const ushort*)WbT,
                                               Cacc, 47040, 1470, 8);
  ep_bf16<<<4096, 256, 0, stream>>>(Cacc, fc6_b, x1bf);
  gemm_bf16<<<dim3(8, 8, 8), 256, 0, stream>>>((const ushort*)x1bf, (const ushort*)fc7T,
                                               Cacc2, 1024, 32, 8);
  ep_f32<<<4096, 256, 0, stream>>>(Cacc2, fc7_b, x2buf);
  out_head<<<1000, 256, 0, stream>>>(x2buf, hd_cls_w, hd_cls_b, hd_bbox_w, hd_bbox_b,
                                     (float*)d_out);
}

// Round 4
// 1687.164 us; speedup vs baseline: 2.9647x; 1.1998x over previous
//
#include <hip/hip_runtime.h>
#include <hip/hip_bf16.h>
#include <cstdint>
#include <cstddef>

// ---------------------------------------------------------------------------
// Vehicle detection pipeline (RPN conv -> heads -> topk -> NMS -> ROI -> FC)
// Conv: 3-way-split bf16 MFMA (b0+b1+b2, 6 products kept, err ~2^-27 —
//       below fp32 reorder noise; round-3's 2-way split at 2^-18 flipped
//       an NMS IoU comparison).
// FC6/FC7: bf16 MFMA GEMMs (post-selection, tolerance-safe).
// ---------------------------------------------------------------------------

typedef __attribute__((ext_vector_type(8))) short short8;
typedef __attribute__((ext_vector_type(4))) float f32x4;

#define CONV_M 1024
#define CONV_N 896
#define CONV_K 8640

__device__ __forceinline__ void gld_lds16(const void* g, void* l)
{
  __builtin_amdgcn_global_load_lds(
      (const __attribute__((address_space(1))) unsigned int*)g,
      (__attribute__((address_space(3))) unsigned int*)l, 16, 0, 0);
}

__device__ __forceinline__ void bf16split3(float v, ushort& o0, ushort& o1, ushort& o2)
{
  __hip_bfloat16 h0 = __float2bfloat16(v);
  float r1 = v - __bfloat162float(h0);
  __hip_bfloat16 h1 = __float2bfloat16(r1);
  float r2 = r1 - __bfloat162float(h1);
  __hip_bfloat16 h2 = __float2bfloat16(r2);
  o0 = *(ushort*)&h0; o1 = *(ushort*)&h1; o2 = *(ushort*)&h2;
}

// ---------------- split conv_w [960][8640] (k=c*9+tap) -> Wsp[3][1024][8640] (k=tap*960+c)
__global__ __launch_bounds__(256) void wsplit(const float* __restrict__ w,
                                              ushort* __restrict__ Wsp)
{
  int idx = blockIdx.x * 256 + threadIdx.x;  // o*960 + c
  if (idx >= 960 * 960) return;
  int c = idx % 960, o = idx / 960;
  const float* src = w + (size_t)o * 8640 + c * 9;
  size_t ob = (size_t)o * 8640 + c;
  const size_t SS = (size_t)CONV_M * CONV_K;
#pragma unroll
  for (int tap = 0; tap < 9; ++tap) {
    ushort b0, b1, b2;
    bf16split3(src[tap], b0, b1, b2);
    Wsp[ob + tap * 960]          = b0;
    Wsp[SS + ob + tap * 960]     = b1;
    Wsp[2 * SS + ob + tap * 960] = b2;
  }
}

// zero pad rows 960..1023 of all 3 W splits
__global__ __launch_bounds__(256) void wzero(ushort* __restrict__ Wsp)
{
  int idx = blockIdx.x * 256 + threadIdx.x;  // 3 * 64 * 8640
  if (idx >= 3 * 64 * 8640) return;
  int s = idx / (64 * 8640);
  int r = idx - s * (64 * 8640);
  Wsp[(size_t)s * CONV_M * CONV_K + (size_t)960 * CONV_K + r] = 0;
}

// ---------------- im2col + 3-split: features -> Xsp[3][2][896][8640] --------
__global__ __launch_bounds__(256) void im2col_split(const float* __restrict__ f,
                                                    ushort* __restrict__ Xsp)
{
  int idx = blockIdx.x * 256 + threadIdx.x;  // (img*896 + p)*960 + c
  if (idx >= 2 * 896 * 960) return;
  int c = idx % 960;
  int r = idx / 960;
  int p = r % 896;
  int img = r / 896;
  const size_t SS = (size_t)2 * CONV_N * CONV_K;
  size_t ob = ((size_t)img * CONV_N + p) * CONV_K + c;
  if (p >= 800) {
#pragma unroll
    for (int tap = 0; tap < 9; ++tap) {
      Xsp[ob + tap * 960] = 0;
      Xsp[SS + ob + tap * 960] = 0;
      Xsp[2 * SS + ob + tap * 960] = 0;
    }
    return;
  }
  int y = p / 40, x = p - (p / 40) * 40;
  const float* fb = f + ((size_t)img * 960 + c) * 800;
#pragma unroll
  for (int ky = 0; ky < 3; ++ky)
#pragma unroll
    for (int kx = 0; kx < 3; ++kx) {
      int yy = y + ky - 1, xx = x + kx - 1;
      float v = (yy >= 0 && yy < 20 && xx >= 0 && xx < 40) ? fb[yy * 40 + xx] : 0.f;
      ushort b0, b1, b2;
      bf16split3(v, b0, b1, b2);
      int tap = ky * 3 + kx;
      Xsp[ob + tap * 960] = b0;
      Xsp[SS + ob + tap * 960] = b1;
      Xsp[2 * SS + ob + tap * 960] = b2;
    }
}

// ---------------- conv as 3-split bf16 MFMA GEMM ----------------------------
// C[img][o][p] (+)= Wsp[wi][o][k] * Xsp[xi][img][p][k];  M=1024, N=896, K=8640.
// grid.z in [0,12): img = z&1, prod = z>>1 over 6 kept split-products.
__global__ __launch_bounds__(256, 2) void conv_gemm(const ushort* __restrict__ Wsp,
                                                    const ushort* __restrict__ Xsp,
                                                    float* __restrict__ Cacc)
{
  __shared__ __align__(16) ushort As[128 * 32];
  __shared__ __align__(16) ushort Bs[128 * 32];
  const int wi_t[6] = {0, 0, 1, 0, 1, 2};
  const int xi_t[6] = {0, 1, 0, 2, 1, 0};
  int z = blockIdx.z;
  int img = z & 1, prod = z >> 1;
  const ushort* A  = Wsp + (size_t)wi_t[prod] * CONV_M * CONV_K;
  const ushort* BT = Xsp + ((size_t)xi_t[prod] * 2 + img) * CONV_N * CONV_K;
  float* C = Cacc + (size_t)img * CONV_M * CONV_N;
  const int Klen = CONV_K;

  int tid = threadIdx.x;
  int wave = tid >> 6, lane = tid & 63;
  int n0 = blockIdx.x * 128, m0 = blockIdx.y * 128;

  const ushort* Ap0 = A  + (size_t)(m0 + wave * 32 + (lane >> 2)) * Klen + ((lane & 3) << 3);
  const ushort* Bp0 = BT + (size_t)(n0 + wave * 32 + (lane >> 2)) * Klen + ((lane & 3) << 3);
  size_t rstep = (size_t)16 * Klen;
  ushort* Al0 = &As[(wave * 32) * 32];
  ushort* Al1 = &As[(wave * 32 + 16) * 32];
  ushort* Bl0 = &Bs[(wave * 32) * 32];
  ushort* Bl1 = &Bs[(wave * 32 + 16) * 32];

  int wm = (wave >> 1) * 64, wn = (wave & 1) * 64;
  int ar = lane & 15, aq = (lane >> 4) << 3;
  f32x4 acc[4][4] = {};

  for (int s = 0; s < CONV_K / 32; ++s) {
    size_t k0 = (size_t)s << 5;
    gld_lds16(Ap0 + k0, Al0);
    gld_lds16(Ap0 + rstep + k0, Al1);
    gld_lds16(Bp0 + k0, Bl0);
    gld_lds16(Bp0 + rstep + k0, Bl1);
    __syncthreads();
    short8 af[4], bfv[4];
#pragma unroll
    for (int mi = 0; mi < 4; ++mi)
      af[mi] = *(const short8*)&As[(wm + mi * 16 + ar) * 32 + aq];
#pragma unroll
    for (int ni = 0; ni < 4; ++ni)
      bfv[ni] = *(const short8*)&Bs[(wn + ni * 16 + ar) * 32 + aq];
#pragma unroll
    for (int mi = 0; mi < 4; ++mi)
#pragma unroll
      for (int ni = 0; ni < 4; ++ni)
        acc[mi][ni] = __builtin_amdgcn_mfma_f32_16x16x32_bf16(af[mi], bfv[ni],
                                                              acc[mi][ni], 0, 0, 0);
    __syncthreads();
  }
  int crow = m0 + wm + ((lane >> 4) << 2);
  int ccol = n0 + wn + (lane & 15);
#pragma unroll
  for (int mi = 0; mi < 4; ++mi)
#pragma unroll
    for (int ni = 0; ni < 4; ++ni) {
      float* cp = &C[(size_t)(crow + mi * 16) * CONV_N + ccol + ni * 16];
      f32x4 v = acc[mi][ni];
      atomicAdd(cp,                v.x);
      atomicAdd(cp + CONV_N,       v.y);
      atomicAdd(cp + 2 * CONV_N,   v.z);
      atomicAdd(cp + 3 * CONV_N,   v.w);
    }
}

// ---------------- conv epilogue: T[img][o][p832] = relu(C + bias) -----------
__global__ __launch_bounds__(256) void conv_ep(const float* __restrict__ Cacc,
                                               const float* __restrict__ bias,
                                               float* __restrict__ T)
{
  int idx = blockIdx.x * 256 + threadIdx.x;  // 2*960*832
  if (idx >= 2 * 960 * 832) return;
  int p = idx % 832;
  int r = idx / 832;
  int o = r % 960;
  int img = r / 960;
  float v = 0.f;
  if (p < 800) v = fmaxf(Cacc[((size_t)img * CONV_M + o) * CONV_N + p] + bias[o], 0.f);
  T[idx] = v;
}

// ---------------- RPN heads as tiled GEMM: 60 outs x 800 px, K=960 ----------
__global__ __launch_bounds__(256) void rpn_gemm(const float* __restrict__ T,
                                                const float* __restrict__ cls_w,
                                                const float* __restrict__ cls_b,
                                                const float* __restrict__ reg_w,
                                                const float* __restrict__ reg_b,
                                                float* __restrict__ obj,
                                                float* __restrict__ dlt)
{
  __shared__ float As[16][64];
  __shared__ float Bs[16][64];
  int img = blockIdx.y, p0 = blockIdx.x * 64;
  int tid = threadIdx.x;
  int aj = tid >> 2, ak = (tid & 3) << 2;
  int bk = tid >> 4, bp = (tid & 15) << 2;
  int ty = tid >> 6, tx = tid & 63;
  float acc[15] = {};
  const float* Tb = T + (size_t)img * 960 * 832;
  for (int k0 = 0; k0 < 960; k0 += 16) {
    if (aj < 60) {
      const float* wrow = (aj < 12) ? cls_w + aj * 960 : reg_w + (aj - 12) * 960;
      float4 wv = *(const float4*)&wrow[k0 + ak];
      As[ak + 0][aj] = wv.x; As[ak + 1][aj] = wv.y;
      As[ak + 2][aj] = wv.z; As[ak + 3][aj] = wv.w;
    }
    *(float4*)&Bs[bk][bp] = *(const float4*)&Tb[(size_t)(k0 + bk) * 832 + p0 + bp];
    __syncthreads();
#pragma unroll
    for (int kk = 0; kk < 16; ++kk) {
      float bv = Bs[kk][tx];
#pragma unroll
      for (int jj = 0; jj < 15; ++jj) acc[jj] += As[kk][jj * 4 + ty] * bv;
    }
    __syncthreads();
  }
  int p = p0 + tx;
  if (p < 800) {
#pragma unroll
    for (int jj = 0; jj < 15; ++jj) {
      int j = jj * 4 + ty;
      float val = acc[jj] + ((j < 12) ? cls_b[j] : reg_b[j - 12]);
      if (j < 12) obj[(size_t)img * 9600 + p * 12 + j] = val;
      else        dlt[(size_t)img * 38400 + p * 48 + (j - 12)] = val;
    }
  }
}

// ---------------- top-k: bitonic sort of packed (score,~idx) keys -----------
__device__ inline unsigned long long pack_key(float v, int g)
{
  unsigned u = __float_as_uint(v);
  u = (u & 0x80000000u) ? ~u : (u | 0x80000000u);
  return ((unsigned long long)u << 32) | (unsigned)(~g);
}

__global__ __launch_bounds__(512) void sort8k(const float* __restrict__ obj,
                                              unsigned long long* __restrict__ topkeys)
{
  __shared__ unsigned long long keys[8192];
  int b = blockIdx.x >> 1, h = blockIdx.x & 1;
  int tid = threadIdx.x;
  for (int i = tid; i < 8192; i += 512) {
    int g = h * 8192 + i;
    unsigned long long key = 0ULL;
    if (g < 9600) key = pack_key(obj[(size_t)b * 9600 + g], g);
    keys[i] = key;
  }
  __syncthreads();
  for (int k = 2; k <= 8192; k <<= 1)
    for (int j = k >> 1; j > 0; j >>= 1) {
      for (int i = tid; i < 8192; i += 512) {
        int ixj = i ^ j;
        if (ixj > i) {
          bool desc = ((i & k) == 0);
          unsigned long long a = keys[i], c = keys[ixj];
          if ((a < c) == desc) { keys[i] = c; keys[ixj] = a; }
        }
      }
      __syncthreads();
    }
  for (int i = tid; i < 1024; i += 512)
    topkeys[(size_t)blockIdx.x * 1024 + i] = keys[i];
}

__global__ __launch_bounds__(256) void merge2k(const unsigned long long* __restrict__ topkeys,
                                               int* __restrict__ selidx)
{
  __shared__ unsigned long long keys[2048];
  int b = blockIdx.x, tid = threadIdx.x;
  for (int i = tid; i < 2048; i += 256) keys[i] = topkeys[(size_t)b * 2048 + i];
  __syncthreads();
  for (int k = 2; k <= 2048; k <<= 1)
    for (int j = k >> 1; j > 0; j >>= 1) {
      for (int i = tid; i < 2048; i += 256) {
        int ixj = i ^ j;
        if (ixj > i) {
          bool desc = ((i & k) == 0);
          unsigned long long a = keys[i], c = keys[ixj];
          if ((a < c) == desc) { keys[i] = c; keys[ixj] = a; }
        }
      }
      __syncthreads();
    }
  for (int i = tid; i < 1000; i += 256)
    selidx[b * 1000 + i] = (int)(~(unsigned)(keys[i] & 0xffffffffULL));
}

// ---------------- decode + clip boxes (ref-exact op order) ------------------
__global__ __launch_bounds__(256) void decode_kernel(const int* __restrict__ selidx,
                                                     const float* __restrict__ dlt,
                                                     float* __restrict__ boxes)
{
#pragma clang fp contract(off)
  int t = blockIdx.x * 256 + threadIdx.x;
  if (t >= 2000) return;
  int b = t / 1000;
  int g = selidx[t];
  int cell = g / 12, a = g - cell * 12;
  int y = cell / 40, x = cell - y * 40;
  int ridx = a >> 2, sidx = a & 3;
  const float sizes_[4]  = {32.f, 64.f, 128.f, 256.f};
  const float ratios_[3] = {0.5f, 1.f, 2.f};
  float size = sizes_[sidx];
  float hr = sqrtf(ratios_[ridx]);
  float wr = 1.f / hr;
  float wsz = wr * size, hsz = hr * size;
  float hw = 0.5f * wsz, hh = 0.5f * hsz;
  float gx = (float)x * 16.f, gy = (float)y * 16.f;
  float a0 = gx - hw, a1 = gy - hh, a2 = gx + hw, a3 = gy + hh;
  float wa = a2 - a0, ha = a3 - a1;
  float cxa = a0 + 0.5f * wa, cya = a1 + 0.5f * ha;
  const float* d = &dlt[(size_t)(b * 9600 + g) * 4];
  float dx = d[0], dy = d[1];
  float dw = fminf(d[2], 4.135166556742356f);
  float dh = fminf(d[3], 4.135166556742356f);
  float cx = dx * wa + cxa;
  float cy = dy * ha + cya;
  float w = expf(dw) * wa;
  float h = expf(dh) * ha;
  float x1 = cx - 0.5f * w, y1 = cy - 0.5f * h;
  float x2 = cx + 0.5f * w, y2 = cy + 0.5f * h;
  x1 = fminf(fmaxf(x1, 0.f), 640.f);
  y1 = fminf(fmaxf(y1, 0.f), 320.f);
  x2 = fminf(fmaxf(x2, 0.f), 640.f);
  y2 = fminf(fmaxf(y2, 0.f), 320.f);
  *(float4*)&boxes[(size_t)t * 4] = make_float4(x1, y1, x2, y2);
}

// ---------------- IoU suppression bit-matrix (j > i, iou > 0.7) -------------
__global__ __launch_bounds__(256) void iou_kernel(const float* __restrict__ boxes,
                                                  unsigned long long* __restrict__ bitrow)
{
#pragma clang fp contract(off)
  int b = blockIdx.y;
  int i = blockIdx.x * 16 + (threadIdx.x >> 4);
  int w = threadIdx.x & 15;
  __shared__ float4 bx[1000];
  for (int t = threadIdx.x; t < 1000; t += 256)
    bx[t] = *(const float4*)&boxes[(size_t)(b * 1000 + t) * 4];
  __syncthreads();
  if (i >= 1000) return;
  float4 bi = bx[i];
  float area_i = (bi.z - bi.x) * (bi.w - bi.y);
  unsigned long long bits = 0ULL;
  for (int t = 0; t < 64; ++t) {
    int j = w * 64 + t;
    if (j > i && j < 1000) {
      float4 bj = bx[j];
      float xx1 = fmaxf(bi.x, bj.x), yy1 = fmaxf(bi.y, bj.y);
      float xx2 = fminf(bi.z, bj.z), yy2 = fminf(bi.w, bj.w);
      float iw = fmaxf(xx2 - xx1, 0.f), ih = fmaxf(yy2 - yy1, 0.f);
      float inter = iw * ih;
      float area_j = (bj.z - bj.x) * (bj.w - bj.y);
      float iou = inter / (area_i + area_j - inter + 1e-6f);
      if (iou > 0.7f) bits |= 1ULL << t;
    }
  }
  bitrow[(size_t)(b * 1000 + i) * 16 + w] = bits;
}

// ---------------- sequential NMS scan + keep-500 + gather props -------------
__device__ inline unsigned long long shfl64(unsigned long long v, int src)
{
  int lo = __shfl((int)(unsigned)(v & 0xffffffffULL), src, 64);
  int hi = __shfl((int)(unsigned)(v >> 32), src, 64);
  return ((unsigned long long)(unsigned)hi << 32) | (unsigned)lo;
}

__global__ __launch_bounds__(64) void nms_scan(const unsigned long long* __restrict__ bitrow,
                                               const float* __restrict__ boxes,
                                               float* __restrict__ props)
{
  int b = blockIdx.x;
  int lane = threadIdx.x;
  unsigned long long alive = 0ULL;
  if (lane < 15) alive = ~0ULL;
  else if (lane == 15) alive = (1ULL << 40) - 1ULL;
  const unsigned long long* rows = bitrow + (size_t)b * 16000;
  for (int i0 = 0; i0 < 1000; i0 += 4) {
    unsigned long long v = rows[i0 * 16 + lane];
#pragma unroll
    for (int s = 0; s < 4; ++s) {
      int i = i0 + s;
      unsigned long long row = shfl64(v, (s << 4) | (lane & 15));
      unsigned long long ow = shfl64(alive, i >> 6);
      if ((ow >> (i & 63)) & 1ULL) alive &= ~row;
    }
  }
  __shared__ unsigned long long am[16];
  __shared__ int keep[500];
  if (lane < 16) am[lane] = alive;
  __syncthreads();
  if (lane == 0) {
    int cnt = 0;
    for (int i = 0; i < 1000 && cnt < 500; ++i)
      if ((am[i >> 6] >> (i & 63)) & 1ULL) keep[cnt++] = i;
    for (int i = 0; i < 1000 && cnt < 500; ++i)
      if (!((am[i >> 6] >> (i & 63)) & 1ULL)) keep[cnt++] = i;
  }
  __syncthreads();
  for (int r = lane; r < 500; r += 64) {
    int g = keep[r];
    *(float4*)&props[(size_t)(b * 500 + r) * 4] =
        *(const float4*)&boxes[(size_t)(b * 1000 + g) * 4];
  }
}

// ---------------- transpose features to (b, p, c) for channel-coalesced ROI -
__global__ __launch_bounds__(256) void transpose_feat(const float* __restrict__ f,
                                                      float* __restrict__ ft)
{
  __shared__ float tile[32][33];
  int b = blockIdx.z;
  int c0 = blockIdx.y * 32, p0 = blockIdx.x * 32;
  int tx = threadIdx.x, ty = threadIdx.y;
  for (int r = ty; r < 32; r += 8)
    tile[r][tx] = f[((size_t)b * 960 + c0 + r) * 800 + p0 + tx];
  __syncthreads();
  for (int r = ty; r < 32; r += 8)
    ft[((size_t)b * 800 + p0 + r) * 960 + c0 + tx] = tile[tx][r];
}

// ---------------- ROI align -> pooled bf16, k' = q*960 + c ------------------
__global__ __launch_bounds__(256) void roi_kernel(const float* __restrict__ ft,
                                                  const float* __restrict__ props,
                                                  __hip_bfloat16* __restrict__ pooled)
{
  int q = blockIdx.x;
  int nr = blockIdx.y;
  __hip_bfloat16* outp = pooled + (size_t)nr * 47040 + q * 960;
  if (nr >= 1000) {
    for (int c = threadIdx.x; c < 960; c += 256) outp[c] = __float2bfloat16(0.f);
    return;
  }
  int b = nr / 500;
  int py = q / 7, px = q - py * 7;
  float4 bx = *(const float4*)&props[(size_t)nr * 4];
  float x1 = bx.x / 16.f, y1 = bx.y / 16.f, x2 = bx.z / 16.f, y2 = bx.w / 16.f;
  float rw = fmaxf(x2 - x1, 1.f), rh = fmaxf(y2 - y1, 1.f);
  float bw = rw / 7.f, bh = rh / 7.f;
  int offs[16]; float wts[16];
#pragma unroll
  for (int s = 0; s < 4; ++s) {
    int sy = s >> 1, sx = s & 1;
    float ys = y1 + ((float)py + (sy ? 0.75f : 0.25f)) * bh;
    float xs = x1 + ((float)px + (sx ? 0.75f : 0.25f)) * bw;
    ys = fminf(fmaxf(ys, 0.f), 19.f);
    xs = fminf(fmaxf(xs, 0.f), 39.f);
    int y0 = (int)floorf(ys), x0 = (int)floorf(xs);
    int y1i = y0 + 1 < 19 ? y0 + 1 : 19;
    int x1i = x0 + 1 < 39 ? x0 + 1 : 39;
    float wy = ys - (float)y0, wx = xs - (float)x0;
    int base0 = y0 * 40, base1 = y1i * 40;
    offs[s * 4 + 0] = base0 + x0;  wts[s * 4 + 0] = 0.25f * (1.f - wy) * (1.f - wx);
    offs[s * 4 + 1] = base0 + x1i; wts[s * 4 + 1] = 0.25f * (1.f - wy) * wx;
    offs[s * 4 + 2] = base1 + x0;  wts[s * 4 + 2] = 0.25f * wy * (1.f - wx);
    offs[s * 4 + 3] = base1 + x1i; wts[s * 4 + 3] = 0.25f * wy * wx;
  }
  const float* fb = ft + (size_t)b * 800 * 960;
  for (int c = threadIdx.x; c < 960; c += 256) {
    float acc = 0.f;
#pragma unroll
    for (int s = 0; s < 16; ++s) acc += wts[s] * fb[(size_t)offs[s] * 960 + c];
    outp[c] = __float2bfloat16(acc);
  }
}

// ---------------- transpose-cast fc6_w -> WbT bf16 [n=1024][k=47040] --------
__global__ __launch_bounds__(256) void cast_w6(const float* __restrict__ w6,
                                               __hip_bfloat16* __restrict__ WbT)
{
  __shared__ float tile[32][33];
  int c0 = blockIdx.x * 32;
  int n0 = blockIdx.y * 32;
  int q  = blockIdx.z;
  int tx = threadIdx.x & 31, ty = threadIdx.x >> 5;
  for (int rr = ty; rr < 32; rr += 8)
    tile[rr][tx] = w6[((size_t)(c0 + rr) * 49 + q) * 1024 + n0 + tx];
  __syncthreads();
  for (int rr = ty; rr < 32; rr += 8)
    WbT[(size_t)(n0 + rr) * 47040 + q * 960 + c0 + tx] = __float2bfloat16(tile[tx][rr]);
}

// ---------------- transpose-cast fc7_w -> fc7T bf16 [n=1024][k=1024] --------
__global__ __launch_bounds__(256) void cast_w7(const float* __restrict__ w7,
                                               __hip_bfloat16* __restrict__ WT)
{
  __shared__ float tile[32][33];
  int k0 = blockIdx.x * 32, n0 = blockIdx.y * 32;
  int tx = threadIdx.x & 31, ty = threadIdx.x >> 5;
  for (int rr = ty; rr < 32; rr += 8)
    tile[rr][tx] = w7[(size_t)(k0 + rr) * 1024 + n0 + tx];
  __syncthreads();
  for (int rr = ty; rr < 32; rr += 8)
    WT[(size_t)(n0 + rr) * 1024 + k0 + tx] = __float2bfloat16(tile[tx][rr]);
}

// ---------------- bf16 MFMA GEMM (N-stride 1024): FC6 / FC7 -----------------
__global__ __launch_bounds__(256, 2) void gemm_bf16(const ushort* __restrict__ A,
                                                    const ushort* __restrict__ BT,
                                                    float* __restrict__ C,
                                                    int Klen, int ksteps, int splitk)
{
  __shared__ __align__(16) ushort As[128 * 32];
  __shared__ __align__(16) ushort Bs[128 * 32];
  int tid = threadIdx.x;
  int wave = tid >> 6, lane = tid & 63;
  int n0 = blockIdx.x * 128, m0 = blockIdx.y * 128;
  int steps_per = (ksteps + splitk - 1) / splitk;
  int s0 = blockIdx.z * steps_per;
  int s1 = min(ksteps, s0 + steps_per);

  const ushort* Ap0 = A  + (size_t)(m0 + wave * 32 + (lane >> 2)) * Klen + ((lane & 3) << 3);
  const ushort* Bp0 = BT + (size_t)(n0 + wave * 32 + (lane >> 2)) * Klen + ((lane & 3) << 3);
  size_t rstep = (size_t)16 * Klen;
  ushort* Al0 = &As[(wave * 32) * 32];
  ushort* Al1 = &As[(wave * 32 + 16) * 32];
  ushort* Bl0 = &Bs[(wave * 32) * 32];
  ushort* Bl1 = &Bs[(wave * 32 + 16) * 32];

  int wm = (wave >> 1) * 64, wn = (wave & 1) * 64;
  int ar = lane & 15, aq = (lane >> 4) << 3;
  f32x4 acc[4][4] = {};

  for (int s = s0; s < s1; ++s) {
    size_t k0 = (size_t)s << 5;
    gld_lds16(Ap0 + k0, Al0);
    gld_lds16(Ap0 + rstep + k0, Al1);
    gld_lds16(Bp0 + k0, Bl0);
    gld_lds16(Bp0 + rstep + k0, Bl1);
    __syncthreads();
    short8 af[4], bfv[4];
#pragma unroll
    for (int mi = 0; mi < 4; ++mi)
      af[mi] = *(const short8*)&As[(wm + mi * 16 + ar) * 32 + aq];
#pragma unroll
    for (int ni = 0; ni < 4; ++ni)
      bfv[ni] = *(const short8*)&Bs[(wn + ni * 16 + ar) * 32 + aq];
#pragma unroll
    for (int mi = 0; mi < 4; ++mi)
#pragma unroll
      for (int ni = 0; ni < 4; ++ni)
        acc[mi][ni] = __builtin_amdgcn_mfma_f32_16x16x32_bf16(af[mi], bfv[ni],
                                                              acc[mi][ni], 0, 0, 0);
    __syncthreads();
  }
  int crow = m0 + wm + ((lane >> 4) << 2);
  int ccol = n0 + wn + (lane & 15);
#pragma unroll
  for (int mi = 0; mi < 4; ++mi)
#pragma unroll
    for (int ni = 0; ni < 4; ++ni) {
      float* cp = &C[(size_t)(crow + mi * 16) * 1024 + ccol + ni * 16];
      f32x4 v = acc[mi][ni];
      atomicAdd(cp,        v.x);
      atomicAdd(cp + 1024, v.y);
      atomicAdd(cp + 2048, v.z);
      atomicAdd(cp + 3072, v.w);
    }
}

// ---------------- epilogues: bias + relu (+cast) ----------------------------
__global__ __launch_bounds__(256) void ep_bf16(const float* __restrict__ Cacc,
                                               const float* __restrict__ bias,
                                               __hip_bfloat16* __restrict__ out)
{
  int idx = blockIdx.x * 256 + threadIdx.x;
  out[idx] = __float2bfloat16(fmaxf(Cacc[idx] + bias[idx & 1023], 0.f));
}

__global__ __launch_bounds__(256) void ep_f32(const float* __restrict__ Cacc,
                                              const float* __restrict__ bias,
                                              float* __restrict__ out)
{
  int idx = blockIdx.x * 256 + threadIdx.x;
  out[idx] = fmaxf(Cacc[idx] + bias[idx & 1023], 0.f);
}

// ---------------- final cls/bbox heads: out (2,500,25) ----------------------
__global__ __launch_bounds__(256) void out_head(const float* __restrict__ x2,
                                                const float* __restrict__ cls_w,
                                                const float* __restrict__ cls_b,
                                                const float* __restrict__ bbox_w,
                                                const float* __restrict__ bbox_b,
                                                float* __restrict__ out)
{
  int n = blockIdx.x;
  __shared__ float xv[1024];
  __shared__ float part[25][8];
  for (int k = threadIdx.x; k < 1024; k += 256) xv[k] = x2[(size_t)n * 1024 + k];
  __syncthreads();
  int j = threadIdx.x >> 3, pp = threadIdx.x & 7;
  if (j < 25) {
    float acc = 0.f;
    if (j < 5) {
      for (int k = pp; k < 1024; k += 8) acc += xv[k] * cls_w[k * 5 + j];
    } else {
      int jj = j - 5;
      for (int k = pp; k < 1024; k += 8) acc += xv[k] * bbox_w[k * 20 + jj];
    }
    part[j][pp] = acc;
  }
  __syncthreads();
  if (threadIdx.x < 25) {
    int j2 = threadIdx.x;
    float s = 0.f;
#pragma unroll
    for (int p = 0; p < 8; ++p) s += part[j2][p];
    s += (j2 < 5) ? cls_b[j2] : bbox_b[j2 - 5];
    out[(size_t)n * 25 + j2] = s;
  }
}

// ---------------------------------------------------------------------------
extern "C" void kernel_launch(void* const* d_in, const int* in_sizes, int n_in,
                              void* d_out, int out_size, void* d_ws, size_t ws_size,
                              hipStream_t stream)
{
  const float* features  = (const float*)d_in[0];
  const float* conv_w    = (const float*)d_in[1];
  const float* conv_b    = (const float*)d_in[2];
  const float* rpn_cls_w = (const float*)d_in[3];
  const float* rpn_cls_b = (const float*)d_in[4];
  const float* rpn_reg_w = (const float*)d_in[5];
  const float* rpn_reg_b = (const float*)d_in[6];
  const float* fc6_w     = (const float*)d_in[7];
  const float* fc6_b     = (const float*)d_in[8];
  const float* fc7_w     = (const float*)d_in[9];
  const float* fc7_b     = (const float*)d_in[10];
  const float* hd_cls_w  = (const float*)d_in[11];
  const float* hd_cls_b  = (const float*)d_in[12];
  const float* hd_bbox_w = (const float*)d_in[13];
  const float* hd_bbox_b = (const float*)d_in[14];

  char* ws = (char*)d_ws;
  size_t off = 0;
  auto alloc = [&](size_t bytes) -> char* {
    char* p = ws + off;
    off += (bytes + 255) & ~(size_t)255;
    return p;
  };
  // ---- persistent buffers ----
  float* T      = (float*)alloc(2ull * 960 * 832 * 4);      // conv output, stride 832
  float* obj    = (float*)alloc(2ull * 9600 * 4);
  float* dlt    = (float*)alloc(2ull * 9600 * 4 * 4);
  unsigned long long* topkeys = (unsigned long long*)alloc(4ull * 1024 * 8);
  int* selidx   = (int*)alloc(2000ull * 4);
  float* boxes  = (float*)alloc(2ull * 1000 * 4 * 4);
  unsigned long long* bitrow = (unsigned long long*)alloc(2ull * 1000 * 16 * 8);
  float* props  = (float*)alloc(2ull * 500 * 4 * 4);
  float* featT  = (float*)alloc(2ull * 800 * 960 * 4);
  __hip_bfloat16* fc7T = (__hip_bfloat16*)alloc(1024ull * 1024 * 2);
  float* Cacc   = (float*)alloc(1024ull * 1024 * 4);
  float* Cacc2  = (float*)alloc(1024ull * 1024 * 4);
  __hip_bfloat16* x1bf = (__hip_bfloat16*)alloc(1024ull * 1024 * 2);
  float* x2buf  = (float*)alloc(1024ull * 1024 * 4);

  // ---- union arena: conv scratch (early) aliased with FC buffers (late) ----
  size_t uoff = off;
  // layout A (conv stage): Xsp[3][2][896][8640], Wsp[3][1024][8640], CaccC[2][1024][896]
  ushort* Xsp  = (ushort*)(ws + uoff);
  ushort* Wsp  = Xsp + 3ull * 2 * CONV_N * CONV_K;
  float*  CaccC = (float*)(Wsp + 3ull * CONV_M * CONV_K);
  // layout B (FC stage)
  __hip_bfloat16* pooled = (__hip_bfloat16*)(ws + uoff);
  __hip_bfloat16* WbT    = pooled + 1024ull * 47040;

  // ---- zero accumulators ----
  hipMemsetAsync(CaccC, 0, 2ull * CONV_M * CONV_N * 4, stream);
  hipMemsetAsync(Cacc,  0, 1024ull * 1024 * 4, stream);
  hipMemsetAsync(Cacc2, 0, 1024ull * 1024 * 4, stream);

  // ---- conv stage (3-split bf16 MFMA, 6 products) ----
  wsplit<<<(960 * 960 + 255) / 256, 256, 0, stream>>>(conv_w, Wsp);
  wzero<<<(3 * 64 * 8640 + 255) / 256, 256, 0, stream>>>(Wsp);
  im2col_split<<<(2 * 896 * 960 + 255) / 256, 256, 0, stream>>>(features, Xsp);
  conv_gemm<<<dim3(7, 8, 12), 256, 0, stream>>>(Wsp, Xsp, CaccC);
  conv_ep<<<(2 * 960 * 832 + 255) / 256, 256, 0, stream>>>(CaccC, conv_b, T);

  // ---- RPN heads + proposals ----
  rpn_gemm<<<dim3(13, 2), 256, 0, stream>>>(T, rpn_cls_w, rpn_cls_b, rpn_reg_w, rpn_reg_b,
                                            obj, dlt);
  sort8k<<<4, 512, 0, stream>>>(obj, topkeys);
  merge2k<<<2, 256, 0, stream>>>(topkeys, selidx);
  decode_kernel<<<8, 256, 0, stream>>>(selidx, dlt, boxes);
  iou_kernel<<<dim3(63, 2), 256, 0, stream>>>(boxes, bitrow);
  nms_scan<<<2, 64, 0, stream>>>(bitrow, boxes, props);

  // ---- ROI + FC stage (overwrites conv scratch; stream-ordered, safe) ----
  transpose_feat<<<dim3(25, 30, 2), dim3(32, 8), 0, stream>>>(features, featT);
  roi_kernel<<<dim3(49, 1024), 256, 0, stream>>>(featT, props, pooled);
  cast_w6<<<dim3(30, 32, 49), 256, 0, stream>>>(fc6_w, WbT);
  cast_w7<<<dim3(32, 32), 256, 0, stream>>>(fc7_w, fc7T);
  gemm_bf16<<<dim3(8, 8, 8), 256, 0, stream>>>((const ushort*)pooled, (const ushort*)WbT,
                                               Cacc, 47040, 1470, 8);
  ep_bf16<<<4096, 256, 0, stream>>>(Cacc, fc6_b, x1bf);
  gemm_bf16<<<dim3(8, 8, 8), 256, 0, stream>>>((const ushort*)x1bf, (const ushort*)fc7T,
                                               Cacc2, 1024, 32, 8);
  ep_f32<<<4096, 256, 0, stream>>>(Cacc2, fc7_b, x2buf);
  out_head<<<1000, 256, 0, stream>>>(x2buf, hd_cls_w, hd_cls_b, hd_bbox_w, hd_bbox_b,
                                     (float*)d_out);
}